// Round 10
// baseline (234.818 us; speedup 1.0000x reference)
//
#include <hip/hip_runtime.h>
#include <math.h>

// Problem constants (match reference setup_inputs)
constexpr int Bn = 131072;   // batch
constexpr int Fn = 1024;     // features (= GEMM K)
constexpr int Tn = 100;      // trees
constexpr int Kn = 32;       // features per tree

constexpr int TP  = 112;           // trees padded to 7*16 (GEMM N)
constexpr int NF  = TP / 16;       // 7 B-fragments
constexpr int BK  = 64;            // floats per row per tile
constexpr int NT  = Fn / BK;       // 16 tiles
constexpr int MW  = 16;            // rows per wave (slim: 1 M-fragment)
constexpr int WPB = 4;
constexpr int BM  = WPB * MW;      // 64 rows per block
constexpr int BLOCK = 256;
constexpr int GRID  = Bn / BM;     // 2048 blocks

typedef __attribute__((ext_vector_type(8))) short bf16x8;
typedef __attribute__((ext_vector_type(4))) float f32x4;

// fp32 -> bf16 round-to-nearest-even
__device__ inline unsigned short f2bf(float f) {
    uint32_t u = __float_as_uint(f);
    return (unsigned short)((u + 0x7FFFu + ((u >> 16) & 1u)) >> 16);
}

__device__ inline bf16x8 cvt8(f32x4 lo, f32x4 hi) {
    bf16x8 v;
    v[0] = (short)f2bf(lo[0]); v[1] = (short)f2bf(lo[1]);
    v[2] = (short)f2bf(lo[2]); v[3] = (short)f2bf(lo[3]);
    v[4] = (short)f2bf(hi[0]); v[5] = (short)f2bf(hi[1]);
    v[6] = (short)f2bf(hi[2]); v[7] = (short)f2bf(hi[3]);
    return v;
}

// ---------------------------------------------------------------------------
// Prep: dense W_T bf16 [TP][Fn] + bias[TP] in workspace (unchanged, validated)
// ---------------------------------------------------------------------------
__global__ __launch_bounds__(64)
void rf_prep(const int* __restrict__ fidx, const float* __restrict__ fthr,
             const float* __restrict__ fw,
             unsigned short* __restrict__ wt, float* __restrict__ bias)
{
    const int t    = blockIdx.x;     // 0..111
    const int lane = threadIdx.x;    // 0..63

    int4 z = make_int4(0, 0, 0, 0);
    int4* rowp = (int4*)(wt + (size_t)t * Fn);
    rowp[lane * 2 + 0] = z;
    rowp[lane * 2 + 1] = z;
    __syncthreads();

    float bsum = 0.f;
    if (t < Tn && lane < Kn) {
        const int   idx = fidx[t * Kn + lane];
        const float w   = fw[t * Kn + lane];
        const float th  = fthr[t * Kn + lane];
        wt[(size_t)t * Fn + idx] = f2bf(w);
        bsum = th * w;
    }
#pragma unroll
    for (int d = 1; d < 64; d <<= 1) bsum += __shfl_xor(bsum, d, 64);
    if (lane == 0) bias[t] = (t < Tn) ? bsum : 0.f;
}

// ---------------------------------------------------------------------------
// R10 = R8 structure with SLIM waves (16 rows/wave) to double occupancy:
// VGPR ~150 -> launch_bounds(256,3) -> 12 waves/CU (vs R8's 8).
// Same phase order as R8 (empirically best GEMM so far), no setprio.
// Per phase: LOADB(t) | READF | vmcnt(14)[A(t+1), issued prev phase] |
//            DSWR(A(t+1)->nxt) | NTLD(t+2) | cvt+MFMA (B drains via reg-dep,
//            never below A(t+2):4).
// ---------------------------------------------------------------------------

#define NTLD4(T, S) do {                                                   \
    const char* _p = paA + (size_t)(T) * 256;                              \
    S##0 = __builtin_nontemporal_load((const f32x4*)(_p + 0 * 16384));     \
    S##1 = __builtin_nontemporal_load((const f32x4*)(_p + 1 * 16384));     \
    S##2 = __builtin_nontemporal_load((const f32x4*)(_p + 2 * 16384));     \
    S##3 = __builtin_nontemporal_load((const f32x4*)(_p + 3 * 16384));     \
} while (0)

#define DSWR4(BUFB, S) do {                                                \
    *(f32x4*)(lbase + (BUFB) + w0) = S##0;                                 \
    *(f32x4*)(lbase + (BUFB) + w1) = S##1;                                 \
    *(f32x4*)(lbase + (BUFB) + w2) = S##2;                                 \
    *(f32x4*)(lbase + (BUFB) + w3) = S##3;                                 \
} while (0)

#define LOADB(T) do {                                                      \
    const char* _q = pbB + (size_t)(T) * 128;                              \
    B00 = *(const bf16x8*)(_q + 0 * 32768);                                \
    B01 = *(const bf16x8*)(_q + 1 * 32768);                                \
    B02 = *(const bf16x8*)(_q + 2 * 32768);                                \
    B03 = *(const bf16x8*)(_q + 3 * 32768);                                \
    B04 = *(const bf16x8*)(_q + 4 * 32768);                                \
    B05 = *(const bf16x8*)(_q + 5 * 32768);                                \
    B06 = *(const bf16x8*)(_q + 6 * 32768);                                \
    B10 = *(const bf16x8*)(_q + 0 * 32768 + 64);                           \
    B11 = *(const bf16x8*)(_q + 1 * 32768 + 64);                           \
    B12 = *(const bf16x8*)(_q + 2 * 32768 + 64);                           \
    B13 = *(const bf16x8*)(_q + 3 * 32768 + 64);                           \
    B14 = *(const bf16x8*)(_q + 4 * 32768 + 64);                           \
    B15 = *(const bf16x8*)(_q + 5 * 32768 + 64);                           \
    B16 = *(const bf16x8*)(_q + 6 * 32768 + 64);                           \
} while (0)

// ds_read lo/hi 16B chunks for k-slice KS (single M-fragment, swizzled)
#define READF(KS, LO, HI, BUFB) do {                                       \
    const char* _b = lbase + (BUFB) + r * 256;                             \
    LO = *(const f32x4*)(_b + ((((KS) * 8 + g2 + 0) ^ r) * 16));           \
    HI = *(const f32x4*)(_b + ((((KS) * 8 + g2 + 1) ^ r) * 16));           \
} while (0)

#define MFMAROW(AF, Ba,Bb,Bc,Bd,Be,Bf,Bg) do {                             \
    acc0 = __builtin_amdgcn_mfma_f32_16x16x32_bf16(AF, Ba, acc0, 0, 0, 0); \
    acc1 = __builtin_amdgcn_mfma_f32_16x16x32_bf16(AF, Bb, acc1, 0, 0, 0); \
    acc2 = __builtin_amdgcn_mfma_f32_16x16x32_bf16(AF, Bc, acc2, 0, 0, 0); \
    acc3 = __builtin_amdgcn_mfma_f32_16x16x32_bf16(AF, Bd, acc3, 0, 0, 0); \
    acc4 = __builtin_amdgcn_mfma_f32_16x16x32_bf16(AF, Be, acc4, 0, 0, 0); \
    acc5 = __builtin_amdgcn_mfma_f32_16x16x32_bf16(AF, Bf, acc5, 0, 0, 0); \
    acc6 = __builtin_amdgcn_mfma_f32_16x16x32_bf16(AF, Bg, acc6, 0, 0, 0); \
} while (0)

// One phase: consume tile TC from buffer CB; wait+write set W (=A(TC+1)) into
// buffer OB; then issue NTLD4(TC+2) into set I; then MFMA.
#define PHASE(TC, CB, OB, W, I) do {                                       \
    LOADB(TC);                                                             \
    READF(0, L0, L1, CB);                                                  \
    READF(1, L2, L3, CB);                                                  \
    if ((TC) + 1 < NT) {                                                   \
        asm volatile("s_waitcnt vmcnt(14)" ::: "memory"); /* A(TC+1) in */ \
        DSWR4(OB, W);                                                      \
    }                                                                      \
    if ((TC) + 2 < NT) NTLD4((TC) + 2, I);                                 \
    {                                                                      \
        bf16x8 _af;                                                        \
        _af = cvt8(L0, L1);                                                \
        MFMAROW(_af, B00, B01, B02, B03, B04, B05, B06);                   \
        _af = cvt8(L2, L3);                                                \
        MFMAROW(_af, B10, B11, B12, B13, B14, B15, B16);                   \
    }                                                                      \
} while (0)

__global__ __launch_bounds__(BLOCK, 3)
void rf_gemm(const float* __restrict__ x,
             const unsigned short* __restrict__ wt,
             const float* __restrict__ bias,
             float* __restrict__ out)
{
    __shared__ float lds[WPB][2][MW * BK];   // 4 waves x 2 x 4 KB = 32 KB

    const int lane = threadIdx.x & 63;
    const int wid  = threadIdx.x >> 6;
    const int rb   = blockIdx.x * BM;
    const int r    = lane & 15;
    const int g    = lane >> 4;
    const int g2   = g * 2;
    const int sub  = lane >> 4;     // staging row-within-quad
    const int c    = lane & 15;     // staging logical 16B chunk

    // staging global base: row rb + wid*16 + sub, byte col c*16
    const char* paA = (const char*)(x + (size_t)(rb + wid * MW + sub) * Fn) + c * 16;
    // B global base: row r of fragment 0, k-offset g*8 shorts
    const char* pbB = (const char*)(wt + (size_t)r * Fn + g * 8);
    // LDS wave base
    char* lbase = (char*)&lds[wid][0][0];

    // ds_write byte offsets: instr i -> row i*4+sub, phys chunk c ^ (row&15)
    const int w0 = (0 * 4 + sub) * 256 + ((c ^ ((0 * 4 + sub) & 15)) * 16);
    const int w1 = (1 * 4 + sub) * 256 + ((c ^ ((1 * 4 + sub) & 15)) * 16);
    const int w2 = (2 * 4 + sub) * 256 + ((c ^ ((2 * 4 + sub) & 15)) * 16);
    const int w3 = (3 * 4 + sub) * 256 + ((c ^ ((3 * 4 + sub) & 15)) * 16);

    f32x4 acc0 = {0,0,0,0}, acc1 = {0,0,0,0}, acc2 = {0,0,0,0},
          acc3 = {0,0,0,0}, acc4 = {0,0,0,0}, acc5 = {0,0,0,0},
          acc6 = {0,0,0,0};

    f32x4 SA0, SA1, SA2, SA3;
    f32x4 SB0, SB1, SB2, SB3;
    f32x4 L0, L1, L2, L3;
    bf16x8 B00, B01, B02, B03, B04, B05, B06;
    bf16x8 B10, B11, B12, B13, B14, B15, B16;

    // Prologue: A(0) -> buf0 (compiler reg-dep wait), A(1) left in flight.
    NTLD4(0, SA);
    DSWR4(0, SA);
    NTLD4(1, SB);

    for (int t = 0; t < NT; t += 2) {
        PHASE(t,     0,    4096, SB, SA);  // consume t; A(t+1)->buf1; issue A(t+2)
        PHASE(t + 1, 4096, 0,    SA, SB);  // consume t+1; A(t+2)->buf0; issue A(t+3)
    }

    // ---- epilogue: ws = acc - bias; p = sigmoid; mean over trees ----
    f32x4 accA[NF] = { acc0, acc1, acc2, acc3, acc4, acc5, acc6 };

    const int col = lane & 15;     // C col = lane&15, row = (lane>>4)*4 + reg
    float psum[4] = {};
#pragma unroll
    for (int f = 0; f < NF; ++f) {
        const int  n     = f * 16 + col;
        const bool valid = n < Tn;
        const float bv   = bias[n];   // zero-padded
#pragma unroll
        for (int q = 0; q < 4; ++q) {
            const float ws = accA[f][q] - bv;
            const float p  = 1.f / (1.f + __expf(-ws));
            if (valid) psum[q] += p;
        }
    }
#pragma unroll
    for (int q = 0; q < 4; ++q)
#pragma unroll
        for (int d = 1; d < 16; d <<= 1)
            psum[q] += __shfl_xor(psum[q], d, 64);

    if (col < 4) {   // lane col==q writes row g*4 + q of this fragment
        const int q   = col;
        const int row = rb + wid * MW + g * 4 + q;
        const float pm = psum[q] * (1.0f / Tn);
        *(float2*)(out + (size_t)row * 2) = make_float2(1.0f - pm, pm);
    }
}

extern "C" void kernel_launch(void* const* d_in, const int* in_sizes, int n_in,
                              void* d_out, int out_size, void* d_ws, size_t ws_size,
                              hipStream_t stream) {
    const float* x    = (const float*)d_in[0];
    const int*   fidx = (const int*)  d_in[1];
    const float* fthr = (const float*)d_in[2];
    const float* fw   = (const float*)d_in[3];
    float*       out  = (float*)d_out;

    unsigned short* wt   = (unsigned short*)d_ws;                       // 229376 B
    float*          bias = (float*)((char*)d_ws + (size_t)TP * Fn * 2); // +448 B

    rf_prep<<<TP, 64, 0, stream>>>(fidx, fthr, fw, wt, bias);
    rf_gemm<<<GRID, BLOCK, 0, stream>>>(x, wt, bias, out);
}

// Round 11
// 143.984 us; speedup vs baseline: 1.6309x; 1.6309x over previous
//
#include <hip/hip_runtime.h>
#include <math.h>

// Problem constants (match reference setup_inputs)
constexpr int Bn = 131072;   // batch
constexpr int Fn = 1024;     // features (= GEMM K)
constexpr int Tn = 100;      // trees
constexpr int Kn = 32;       // features per tree

constexpr int TP  = 112;           // trees padded to 7*16 (GEMM N)
constexpr int NF  = TP / 16;       // 7 B-fragments
constexpr int BK  = 64;            // floats per row per tile
constexpr int NT  = Fn / BK;       // 16 tiles
constexpr int BM  = 128;           // rows per block
constexpr int MW  = 32;            // rows per wave (wave-private)
constexpr int WPB = 4;
constexpr int BLOCK = 256;
constexpr int GRID  = Bn / BM;     // 1024 blocks

typedef __attribute__((ext_vector_type(8))) short bf16x8;
typedef __attribute__((ext_vector_type(4))) float f32x4;

using gptr_t = const __attribute__((address_space(1))) void*;
using lptr_t = __attribute__((address_space(3))) void*;

// fp32 -> bf16 round-to-nearest-even
__device__ inline unsigned short f2bf(float f) {
    uint32_t u = __float_as_uint(f);
    return (unsigned short)((u + 0x7FFFu + ((u >> 16) & 1u)) >> 16);
}

__device__ inline bf16x8 cvt8(f32x4 lo, f32x4 hi) {
    bf16x8 v;
    v[0] = (short)f2bf(lo[0]); v[1] = (short)f2bf(lo[1]);
    v[2] = (short)f2bf(lo[2]); v[3] = (short)f2bf(lo[3]);
    v[4] = (short)f2bf(hi[0]); v[5] = (short)f2bf(hi[1]);
    v[6] = (short)f2bf(hi[2]); v[7] = (short)f2bf(hi[3]);
    return v;
}

// ---------------------------------------------------------------------------
// Prep: dense W_T bf16 [TP][Fn] + bias[TP] in workspace (unchanged, validated)
// ---------------------------------------------------------------------------
__global__ __launch_bounds__(64)
void rf_prep(const int* __restrict__ fidx, const float* __restrict__ fthr,
             const float* __restrict__ fw,
             unsigned short* __restrict__ wt, float* __restrict__ bias)
{
    const int t    = blockIdx.x;     // 0..111
    const int lane = threadIdx.x;    // 0..63

    int4 z = make_int4(0, 0, 0, 0);
    int4* rowp = (int4*)(wt + (size_t)t * Fn);
    rowp[lane * 2 + 0] = z;
    rowp[lane * 2 + 1] = z;
    __syncthreads();

    float bsum = 0.f;
    if (t < Tn && lane < Kn) {
        const int   idx = fidx[t * Kn + lane];
        const float w   = fw[t * Kn + lane];
        const float th  = fthr[t * Kn + lane];
        wt[(size_t)t * Fn + idx] = f2bf(w);
        bsum = th * w;
    }
#pragma unroll
    for (int d = 1; d < 64; d <<= 1) bsum += __shfl_xor(bsum, d, 64);
    if (lane == 0) bias[t] = (t < Tn) ? bsum : 0.f;
}

// ---------------------------------------------------------------------------
// R11 = R8 GEMM with HYBRID staging (dual read-queue test):
//   rows 0-15 of each wave tile: global_load_lds DMA (swizzled SOURCE,
//     linear LDS dest - G21 both-sides rule)
//   rows 16-31: nontemporal per-lane dwordx4 (swizzled source) -> named regs
//     -> ds_write_b128 at phys chunk c (same logical<->phys involution)
// Both halves read with the same XOR-swizzled ds_read_b128 (2-way, free).
// Phase t: LOADB(t) | READF x8 (tile t) | vmcnt(14) [drains DMA(t+1)+NT(t+1),
//   leaves B(t)] | DSWR4(NT(t+1) -> O) | lgkmcnt(0) [READF sampled before C
//   frag0 overwrite] | DMA4(t+2 -> C) | NTLD4(t+2 -> S) | cvt+MFMA (B(t)
//   drains by reg-dep to vmcnt(8): A(t+2) stays in flight across phases).
// ---------------------------------------------------------------------------

#define DMA4(T, BUFB) do {                                                  \
    __builtin_amdgcn_global_load_lds((gptr_t)(pd0 + (size_t)(T) * 256),     \
        (lptr_t)(lbase + (BUFB) + 0 * 1024), 16, 0, 0);                     \
    __builtin_amdgcn_global_load_lds((gptr_t)(pd1 + (size_t)(T) * 256),     \
        (lptr_t)(lbase + (BUFB) + 1 * 1024), 16, 0, 0);                     \
    __builtin_amdgcn_global_load_lds((gptr_t)(pd2 + (size_t)(T) * 256),     \
        (lptr_t)(lbase + (BUFB) + 2 * 1024), 16, 0, 0);                     \
    __builtin_amdgcn_global_load_lds((gptr_t)(pd3 + (size_t)(T) * 256),     \
        (lptr_t)(lbase + (BUFB) + 3 * 1024), 16, 0, 0);                     \
} while (0)

#define NTLD4(T) do {                                                       \
    S0 = __builtin_nontemporal_load((const f32x4*)(pn0 + (size_t)(T)*256)); \
    S1 = __builtin_nontemporal_load((const f32x4*)(pn1 + (size_t)(T)*256)); \
    S2 = __builtin_nontemporal_load((const f32x4*)(pn2 + (size_t)(T)*256)); \
    S3 = __builtin_nontemporal_load((const f32x4*)(pn3 + (size_t)(T)*256)); \
} while (0)

#define DSWR4(BUFB) do {                                                    \
    *(f32x4*)(lbase + (BUFB) + w0) = S0;                                    \
    *(f32x4*)(lbase + (BUFB) + w1) = S1;                                    \
    *(f32x4*)(lbase + (BUFB) + w2) = S2;                                    \
    *(f32x4*)(lbase + (BUFB) + w3) = S3;                                    \
} while (0)

#define LOADB(T) do {                                                       \
    const char* _q = pbB + (size_t)(T) * 128;                               \
    B00 = *(const bf16x8*)(_q + 0 * 32768);                                 \
    B01 = *(const bf16x8*)(_q + 1 * 32768);                                 \
    B02 = *(const bf16x8*)(_q + 2 * 32768);                                 \
    B03 = *(const bf16x8*)(_q + 3 * 32768);                                 \
    B04 = *(const bf16x8*)(_q + 4 * 32768);                                 \
    B05 = *(const bf16x8*)(_q + 5 * 32768);                                 \
    B06 = *(const bf16x8*)(_q + 6 * 32768);                                 \
    B10 = *(const bf16x8*)(_q + 0 * 32768 + 64);                            \
    B11 = *(const bf16x8*)(_q + 1 * 32768 + 64);                            \
    B12 = *(const bf16x8*)(_q + 2 * 32768 + 64);                            \
    B13 = *(const bf16x8*)(_q + 3 * 32768 + 64);                            \
    B14 = *(const bf16x8*)(_q + 4 * 32768 + 64);                            \
    B15 = *(const bf16x8*)(_q + 5 * 32768 + 64);                            \
    B16 = *(const bf16x8*)(_q + 6 * 32768 + 64);                            \
} while (0)

#define READF(M, KS, LO, HI, BUFB) do {                                     \
    const char* _b = lbase + (BUFB) + ((M) * 16 + r) * 256;                 \
    LO = *(const f32x4*)(_b + ((((KS) * 8 + g2 + 0) ^ r) * 16));            \
    HI = *(const f32x4*)(_b + ((((KS) * 8 + g2 + 1) ^ r) * 16));            \
} while (0)

#define MFMAROW(AF, Ba,Bb,Bc,Bd,Be,Bf,Bg, a0,a1,a2,a3,a4,a5,a6) do {        \
    a0 = __builtin_amdgcn_mfma_f32_16x16x32_bf16(AF, Ba, a0, 0, 0, 0);      \
    a1 = __builtin_amdgcn_mfma_f32_16x16x32_bf16(AF, Bb, a1, 0, 0, 0);      \
    a2 = __builtin_amdgcn_mfma_f32_16x16x32_bf16(AF, Bc, a2, 0, 0, 0);      \
    a3 = __builtin_amdgcn_mfma_f32_16x16x32_bf16(AF, Bd, a3, 0, 0, 0);      \
    a4 = __builtin_amdgcn_mfma_f32_16x16x32_bf16(AF, Be, a4, 0, 0, 0);      \
    a5 = __builtin_amdgcn_mfma_f32_16x16x32_bf16(AF, Bf, a5, 0, 0, 0);      \
    a6 = __builtin_amdgcn_mfma_f32_16x16x32_bf16(AF, Bg, a6, 0, 0, 0);      \
} while (0)

// One phase: consume tile TC from buffer CB; stage t+1 frag1 into OB;
// issue tile t+2 (DMA into CB frag0, NT into S regs).
#define PHASE(TC, CB, OB) do {                                              \
    LOADB(TC);                                                              \
    READF(0, 0, L0, L1, CB);                                                \
    READF(1, 0, L2, L3, CB);                                                \
    READF(0, 1, L4, L5, CB);                                                \
    READF(1, 1, L6, L7, CB);                                                \
    if ((TC) + 1 < NT) {                                                    \
        asm volatile("s_waitcnt vmcnt(14)" ::: "memory"); /* A(t+1) in */   \
        DSWR4(OB);                                                          \
    }                                                                       \
    asm volatile("s_waitcnt lgkmcnt(0)" ::: "memory");   /* READF sampled */\
    if ((TC) + 2 < NT) {                                                    \
        DMA4((TC) + 2, CB);                                                 \
        NTLD4((TC) + 2);                                                    \
    }                                                                       \
    {                                                                       \
        bf16x8 _af;                                                         \
        _af = cvt8(L0, L1);                                                 \
        MFMAROW(_af, B00, B01, B02, B03, B04, B05, B06,                     \
                acc00, acc01, acc02, acc03, acc04, acc05, acc06);           \
        _af = cvt8(L2, L3);                                                 \
        MFMAROW(_af, B00, B01, B02, B03, B04, B05, B06,                     \
                acc10, acc11, acc12, acc13, acc14, acc15, acc16);           \
        _af = cvt8(L4, L5);                                                 \
        MFMAROW(_af, B10, B11, B12, B13, B14, B15, B16,                     \
                acc00, acc01, acc02, acc03, acc04, acc05, acc06);           \
        _af = cvt8(L6, L7);                                                 \
        MFMAROW(_af, B10, B11, B12, B13, B14, B15, B16,                     \
                acc10, acc11, acc12, acc13, acc14, acc15, acc16);           \
    }                                                                       \
} while (0)

__global__ __launch_bounds__(BLOCK)
void rf_gemm(const float* __restrict__ x,
             const unsigned short* __restrict__ wt,
             const float* __restrict__ bias,
             float* __restrict__ out)
{
    __shared__ float lds[WPB][2][MW * BK];   // 4 waves x 2 x 8 KB = 64 KB

    const int lane = threadIdx.x & 63;
    const int wid  = threadIdx.x >> 6;
    const int rb   = blockIdx.x * BM;
    const int r    = lane & 15;
    const int g    = lane >> 4;
    const int g2   = g * 2;
    const int sub  = lane >> 4;     // staging row-within-quad (0..3)
    const int c    = lane & 15;     // staging phys 16B chunk

    // DMA source pointers (rows 0-15, frag 0): instr i covers rows i*4+sub.
    // Source chunk pre-swizzled: logical = c ^ (row & 15); LDS dest linear.
    const char* xbase = (const char*)(x) + (size_t)(rb + wid * MW) * Fn * 4;
    const char* pd0 = xbase + (size_t)(0 * 4 + sub) * (Fn * 4) + ((c ^ ((0 * 4 + sub) & 15)) * 16);
    const char* pd1 = xbase + (size_t)(1 * 4 + sub) * (Fn * 4) + ((c ^ ((1 * 4 + sub) & 15)) * 16);
    const char* pd2 = xbase + (size_t)(2 * 4 + sub) * (Fn * 4) + ((c ^ ((2 * 4 + sub) & 15)) * 16);
    const char* pd3 = xbase + (size_t)(3 * 4 + sub) * (Fn * 4) + ((c ^ ((3 * 4 + sub) & 15)) * 16);
    // NT source pointers (rows 16-31, frag 1): same swizzle key (row&15).
    const char* pn0 = pd0 + (size_t)16 * Fn * 4;
    const char* pn1 = pd1 + (size_t)16 * Fn * 4;
    const char* pn2 = pd2 + (size_t)16 * Fn * 4;
    const char* pn3 = pd3 + (size_t)16 * Fn * 4;
    // B global base: row r of fragment 0, k-offset g*8 shorts
    const char* pbB = (const char*)(wt + (size_t)r * Fn + g * 8);
    // LDS wave base
    char* lbase = (char*)&lds[wid][0][0];

    // ds_write offsets for NT half: row = 16 + i*4 + sub, phys chunk c
    const int w0 = (16 + 0 * 4 + sub) * 256 + c * 16;
    const int w1 = (16 + 1 * 4 + sub) * 256 + c * 16;
    const int w2 = (16 + 2 * 4 + sub) * 256 + c * 16;
    const int w3 = (16 + 3 * 4 + sub) * 256 + c * 16;

    f32x4 acc00 = {0,0,0,0}, acc01 = {0,0,0,0}, acc02 = {0,0,0,0},
          acc03 = {0,0,0,0}, acc04 = {0,0,0,0}, acc05 = {0,0,0,0},
          acc06 = {0,0,0,0};
    f32x4 acc10 = {0,0,0,0}, acc11 = {0,0,0,0}, acc12 = {0,0,0,0},
          acc13 = {0,0,0,0}, acc14 = {0,0,0,0}, acc15 = {0,0,0,0},
          acc16 = {0,0,0,0};

    f32x4 S0, S1, S2, S3;
    f32x4 L0, L1, L2, L3, L4, L5, L6, L7;
    bf16x8 B00, B01, B02, B03, B04, B05, B06;
    bf16x8 B10, B11, B12, B13, B14, B15, B16;

    // Prologue: tile 0 fully staged into buf0 (DSWR reg-dep drains DMA(0)+NT(0));
    // tile 1 DMA+NT left in flight.  Queue after: [DMA(1):4, NT(1):4].
    DMA4(0, 0);
    NTLD4(0);
    DSWR4(0);
    DMA4(1, 8192);
    NTLD4(1);

    for (int t = 0; t < NT; t += 2) {
        PHASE(t,     0,    8192);   // consume t (buf0); frag1(t+1)->buf1; issue t+2
        PHASE(t + 1, 8192, 0);      // consume t+1 (buf1); frag1(t+2)->buf0; issue t+3
    }

    // ---- epilogue: ws = acc - bias; p = sigmoid; mean over trees ----
    f32x4 accA[2][NF] = {
        { acc00, acc01, acc02, acc03, acc04, acc05, acc06 },
        { acc10, acc11, acc12, acc13, acc14, acc15, acc16 }
    };

    const int col = lane & 15;     // C col = lane&15, row = (lane>>4)*4 + reg
    float psum[2][4] = {};
#pragma unroll
    for (int f = 0; f < NF; ++f) {
        const int  n     = f * 16 + col;
        const bool valid = n < Tn;
        const float bv   = bias[n];   // zero-padded
#pragma unroll
        for (int m = 0; m < 2; ++m)
#pragma unroll
            for (int q = 0; q < 4; ++q) {
                const float ws = accA[m][f][q] - bv;
                const float p  = 1.f / (1.f + __expf(-ws));
                if (valid) psum[m][q] += p;
            }
    }
#pragma unroll
    for (int m = 0; m < 2; ++m)
#pragma unroll
        for (int q = 0; q < 4; ++q)
#pragma unroll
            for (int d = 1; d < 16; d <<= 1)
                psum[m][q] += __shfl_xor(psum[m][q], d, 64);

#pragma unroll
    for (int m = 0; m < 2; ++m) {
        if (col < 4) {   // lane col==q writes row g*4 + q of this fragment
            const int q   = col;
            const int row = rb + wid * MW + m * 16 + g * 4 + q;
            const float pm = psum[m][q] * (1.0f / Tn);
            *(float2*)(out + (size_t)row * 2) = make_float2(1.0f - pm, pm);
        }
    }
}

extern "C" void kernel_launch(void* const* d_in, const int* in_sizes, int n_in,
                              void* d_out, int out_size, void* d_ws, size_t ws_size,
                              hipStream_t stream) {
    const float* x    = (const float*)d_in[0];
    const int*   fidx = (const int*)  d_in[1];
    const float* fthr = (const float*)d_in[2];
    const float* fw   = (const float*)d_in[3];
    float*       out  = (float*)d_out;

    unsigned short* wt   = (unsigned short*)d_ws;                       // 229376 B
    float*          bias = (float*)((char*)d_ws + (size_t)TP * Fn * 2); // +448 B

    rf_prep<<<TP, 64, 0, stream>>>(fidx, fthr, fw, wt, bias);
    rf_gemm<<<GRID, BLOCK, 0, stream>>>(x, wt, bias, out);
}

// Round 12
// 139.267 us; speedup vs baseline: 1.6861x; 1.0339x over previous
//
#include <hip/hip_runtime.h>
#include <math.h>

// Problem constants (match reference setup_inputs)
constexpr int Bn = 131072;   // batch
constexpr int Fn = 1024;     // features
constexpr int Tn = 100;      // trees
constexpr int Kn = 32;       // features per tree

constexpr int BLOCK = 256;
constexpr int WPB   = BLOCK / 64;   // 4 waves/block
constexpr int GRID  = 1024;         // 4 blocks/CU
constexpr int NW    = GRID * WPB;   // 4096 waves
constexpr int RPW   = Bn / NW;      // 32 rows per wave, exact

typedef __attribute__((ext_vector_type(4))) float f32x4;

// Load one 4KB row into 4 named f32x4 regs (nt: bypass cache allocation)
#define NTLD(D0, D1, D2, D3, PTR) do {                       \
    const f32x4* _s = (const f32x4*)(PTR);                   \
    D0 = __builtin_nontemporal_load(_s + lane);              \
    D1 = __builtin_nontemporal_load(_s + 64 + lane);         \
    D2 = __builtin_nontemporal_load(_s + 128 + lane);        \
    D3 = __builtin_nontemporal_load(_s + 192 + lane);        \
} while (0)

// Write the 4 regs to this wave's LDS row buffer (4 x ds_write_b128, linear)
#define DSWR(BUFP, R0, R1, R2, R3) do {                      \
    f32x4* _d = (f32x4*)(BUFP);                              \
    _d[lane]       = R0;                                     \
    _d[64 + lane]  = R1;                                     \
    _d[128 + lane] = R2;                                     \
    _d[192 + lane] = R3;                                     \
} while (0)

// Gather-dot both trees, sigmoid, 64-lane reduce, lane0 stores float2
#define GATHER_COMPUTE(BUFP, ROW) do {                                     \
    const char* _cb = (const char*)(BUFP);                                 \
    float _a0 = 0.f, _a1 = 0.f;                                            \
    _Pragma("unroll")                                                      \
    for (int _k = 0; _k < Kn; ++_k) {                                      \
        const uint32_t _u0 = pk0[_k];                                      \
        const uint32_t _u1 = pk1[_k];                                      \
        _a0 = fmaf(*(const float*)(_cb + (_u0 & 0xFFFu)),                  \
                   __uint_as_float(_u0 & 0xFFFFF000u), _a0);               \
        _a1 = fmaf(*(const float*)(_cb + (_u1 & 0xFFFu)),                  \
                   __uint_as_float(_u1 & 0xFFFFF000u), _a1);               \
    }                                                                      \
    const float _p0 = 1.f / (1.f + __expf(-(_a0 - bias0)));                \
    const float _p1 = 1.f / (1.f + __expf(-(_a1 - bias1)));                \
    float _s = _p0 + (has1 ? _p1 : 0.f);                                   \
    _Pragma("unroll")                                                      \
    for (int _d = 1; _d < 64; _d <<= 1) _s += __shfl_xor(_s, _d, 64);      \
    if (lane == 0) {                                                       \
        const float _pm = _s * (1.0f / Tn);                                \
        *(float2*)(out + (size_t)(ROW) * 2) = make_float2(1.0f - _pm, _pm);\
    }                                                                      \
} while (0)

__global__ __launch_bounds__(BLOCK)
void rf_fwd(const float* __restrict__ x,
            const int*   __restrict__ fidx,
            const float* __restrict__ fthr,
            const float* __restrict__ fw,
            float*       __restrict__ out)
{
    __shared__ float ldsbuf[WPB][2][Fn];   // 32 KB/block

    const int lane  = threadIdx.x & 63;
    const int wid   = threadIdx.x >> 6;
    const int gwave = blockIdx.x * WPB + wid;   // 0..4095

    // Lane handles tree t0 = lane, and t1 = 64+lane when it exists.
    const int  t0   = lane;
    const bool has1 = (64 + lane) < Tn;
    const int  t1   = has1 ? (64 + lane) : lane;

    // ---- Packed per-lane tables: u32 = (w & 0xFFFFF000) | (idx*4) ----
    // w truncated to 11 mantissa bits (rel err <= 2.4e-4); idx*4 = byte offset.
    uint32_t pk0[Kn], pk1[Kn];
    float bias0 = 0.f, bias1 = 0.f;

#pragma unroll
    for (int k = 0; k < Kn; k += 4) {
        int4   i4 = *(const int4*)  (fidx + t0 * Kn + k);
        float4 wv = *(const float4*)(fw   + t0 * Kn + k);
        float4 th = *(const float4*)(fthr + t0 * Kn + k);
        uint32_t wb0 = __float_as_uint(wv.x) & 0xFFFFF000u;
        uint32_t wb1 = __float_as_uint(wv.y) & 0xFFFFF000u;
        uint32_t wb2 = __float_as_uint(wv.z) & 0xFFFFF000u;
        uint32_t wb3 = __float_as_uint(wv.w) & 0xFFFFF000u;
        pk0[k+0] = wb0 | ((uint32_t)i4.x << 2);
        pk0[k+1] = wb1 | ((uint32_t)i4.y << 2);
        pk0[k+2] = wb2 | ((uint32_t)i4.z << 2);
        pk0[k+3] = wb3 | ((uint32_t)i4.w << 2);
        bias0 += th.x*__uint_as_float(wb0) + th.y*__uint_as_float(wb1)
               + th.z*__uint_as_float(wb2) + th.w*__uint_as_float(wb3);
    }
#pragma unroll
    for (int k = 0; k < Kn; k += 4) {
        int4   i4 = *(const int4*)  (fidx + t1 * Kn + k);
        float4 wv = *(const float4*)(fw   + t1 * Kn + k);
        float4 th = *(const float4*)(fthr + t1 * Kn + k);
        uint32_t wb0 = __float_as_uint(wv.x) & 0xFFFFF000u;
        uint32_t wb1 = __float_as_uint(wv.y) & 0xFFFFF000u;
        uint32_t wb2 = __float_as_uint(wv.z) & 0xFFFFF000u;
        uint32_t wb3 = __float_as_uint(wv.w) & 0xFFFFF000u;
        pk1[k+0] = wb0 | ((uint32_t)i4.x << 2);
        pk1[k+1] = wb1 | ((uint32_t)i4.y << 2);
        pk1[k+2] = wb2 | ((uint32_t)i4.z << 2);
        pk1[k+3] = wb3 | ((uint32_t)i4.w << 2);
        bias1 += th.x*__uint_as_float(wb0) + th.y*__uint_as_float(wb1)
               + th.z*__uint_as_float(wb2) + th.w*__uint_as_float(wb3);
    }

    float* buf0 = &ldsbuf[wid][0][0];
    float* buf1 = &ldsbuf[wid][1][0];

    // Wave's rows: gwave + i*NW, i = 0..RPW-1 (exact, no guards needed)
    const float*  row0   = x + (size_t)gwave * Fn;
    const size_t  rstr   = (size_t)NW * Fn;

    f32x4 A0, A1, A2, A3, B0, B1, B2, B3;

    // Prologue: rows i=0 (A) and i=1 (B) in flight
    NTLD(A0, A1, A2, A3, row0);
    NTLD(B0, B1, B2, B3, row0 + rstr);

    for (int i = 0; i < RPW; i += 2) {
        // ---- even: row i (A-set) -> buf0 ----
        DSWR(buf0, A0, A1, A2, A3);            // compiler waits vmcnt for A here
        if (i + 2 < RPW)
            NTLD(A0, A1, A2, A3, row0 + (size_t)(i + 2) * rstr);
        GATHER_COMPUTE(buf0, gwave + (size_t)i * NW);   // lgkm-ordered by compiler

        // ---- odd: row i+1 (B-set) -> buf1 ----
        DSWR(buf1, B0, B1, B2, B3);
        if (i + 3 < RPW)
            NTLD(B0, B1, B2, B3, row0 + (size_t)(i + 3) * rstr);
        GATHER_COMPUTE(buf1, gwave + (size_t)(i + 1) * NW);
    }
}

extern "C" void kernel_launch(void* const* d_in, const int* in_sizes, int n_in,
                              void* d_out, int out_size, void* d_ws, size_t ws_size,
                              hipStream_t stream) {
    const float* x    = (const float*)d_in[0];
    const int*   fidx = (const int*)  d_in[1];
    const float* fthr = (const float*)d_in[2];
    const float* fw   = (const float*)d_in[3];
    float*       out  = (float*)d_out;

    rf_fwd<<<GRID, BLOCK, 0, stream>>>(x, fidx, fthr, fw, out);
}